// Round 11
// baseline (562.007 us; speedup 1.0000x reference)
//
#include <hip/hip_runtime.h>
#include <hip/hip_bf16.h>

// MoE top-1, E=2: out[t,:] = x[t,:] @ We[e*] + be[e*],  e* = argmax(x[t]@Wg + bg)
//
// moe_gemm R11: NO LDS in the K-loop. Each lane loads its MFMA fragments
// directly from global (L2-resident panels, 16x64B segments/instruction),
// register-double-buffered distance-1. Zero barriers / vmcnt discipline in
// the main loop -- the barrier-drain stall class is structurally eliminated.
// LDS used only for the epilogue transpose. Supertile XCD map (R7-confirmed).

#define DM 1024
#define DH 4096
#define KS 32
#define NS (DM / KS)   // 32 K-steps

typedef __attribute__((ext_vector_type(4))) float f32x4;
typedef __attribute__((ext_vector_type(8))) __bf16 bf16x8;

__device__ __forceinline__ unsigned short f2bf(float f) {
    union { float f; unsigned u; } a; a.f = f;
    unsigned u = a.u;
    u += 0x7fffu + ((u >> 16) & 1u);   // RNE
    return (unsigned short)(u >> 16);
}

// ---------------- prep: We transpose (bid<512) | gate+convert+scatter (bid>=512) ----------------
__global__ __launch_bounds__(1024) void prep(
    const float* __restrict__ x, const float* __restrict__ Wg,
    const float* __restrict__ bg, const float* __restrict__ We, int T,
    unsigned short* __restrict__ xbf, unsigned short* __restrict__ webt,
    int* __restrict__ perm, int* __restrict__ eidx, int* __restrict__ cur)
{
    int bid = blockIdx.x, tid = threadIdx.x;

    if (bid < 512) {
        // ---- We [2][1024][4096] f32 -> webt [2][4096][1024] bf16, 4 64x64 tiles/block ----
        __shared__ unsigned short tile[4][64][72];
        int sub = tid >> 8, t2 = tid & 255;
        int g = bid * 4 + sub;
        int e = g >> 10, rr = g & 1023, kt = rr >> 6, ht = rr & 63;
        int k0 = kt * 64, h0 = ht * 64;
        int k = t2 >> 2, hc = t2 & 3;
        const float* src = We + ((size_t)e * DM + k0 + k) * DH + h0 + hc * 16;
#pragma unroll
        for (int j = 0; j < 4; ++j) {
            f32x4 v = *(const f32x4*)(src + j * 4);
#pragma unroll
            for (int q = 0; q < 4; ++q)
                tile[sub][hc * 16 + j * 4 + q][k] = f2bf(v[q]);
        }
        __syncthreads();
        int h = t2 >> 2, kc = t2 & 3;
        unsigned short* dst = webt + ((size_t)e * DH + h0 + h) * DM + k0 + kc * 16;
        *(uint4*)(dst)     = *(const uint4*)&tile[sub][h][kc * 16];
        *(uint4*)(dst + 8) = *(const uint4*)&tile[sub][h][kc * 16 + 8];
        return;
    }

    // ---- gate: 64 tokens/block, 16 waves x 4 tokens; 2 atomics/block (G12) ----
    __shared__ unsigned char eL[64];
    int gb = bid - 512;                 // 0..255
    int lane = tid & 63, w = tid >> 6;  // 16 waves
    float wgv[32];                      // Wg rows 2c,2c+1 for this lane's 16 cols
#pragma unroll
    for (int j = 0; j < 8; ++j)
        *(f32x4*)&wgv[j * 4] = *(const f32x4*)(Wg + lane * 32 + j * 4);
    float bg0 = bg[0], bg1 = bg[1];
    int t0 = gb * 64 + w * 4;
#pragma unroll
    for (int tl = 0; tl < 4; ++tl) {
        int t = t0 + tl;
        const float* xr = x + (size_t)t * DM + lane * 16;
        double g0 = 0.0, g1 = 0.0;
        unsigned hw[8];
#pragma unroll
        for (int j = 0; j < 4; ++j) {
            f32x4 v = *(const f32x4*)(xr + j * 4);
#pragma unroll
            for (int q = 0; q < 4; ++q) {
                g0 += (double)v[q] * (double)wgv[2 * (j * 4 + q)];
                g1 += (double)v[q] * (double)wgv[2 * (j * 4 + q) + 1];
            }
            hw[j * 2]     = (unsigned)f2bf(v[0]) | ((unsigned)f2bf(v[1]) << 16);
            hw[j * 2 + 1] = (unsigned)f2bf(v[2]) | ((unsigned)f2bf(v[3]) << 16);
        }
        unsigned short* xw = xbf + (size_t)t * DM + lane * 16;
        uint4 u0; u0.x = hw[0]; u0.y = hw[1]; u0.z = hw[2]; u0.w = hw[3];
        uint4 u1; u1.x = hw[4]; u1.y = hw[5]; u1.z = hw[6]; u1.w = hw[7];
        *(uint4*)(xw)     = u0;
        *(uint4*)(xw + 8) = u1;
#pragma unroll
        for (int off = 32; off; off >>= 1) {
            g0 += __shfl_xor(g0, off);
            g1 += __shfl_xor(g1, off);
        }
        if (lane == 0) {
            int ee = ((g1 + (double)bg1) > (g0 + (double)bg0)) ? 1 : 0;  // tie -> e0
            eidx[t] = ee;
            eL[w * 4 + tl] = (unsigned char)ee;
        }
    }
    __syncthreads();
    if (w == 0) {
        int myE = eL[lane];
        unsigned long long m1 = __ballot(myE != 0);
        int tot1 = __popcll(m1);
        int b0 = 0, b1 = 0;
        if (lane == 0) {
            b0 = atomicAdd(cur, 64 - tot1);
            b1 = atomicAdd(cur + 1, tot1);
        }
        b0 = __shfl(b0, 0);
        b1 = __shfl(b1, 0);
        unsigned long long lm = (1ull << lane) - 1ull;
        int rank = __popcll((myE ? m1 : ~m1) & lm);
        int dstp = myE ? (T - b1 - tot1 + rank) : (b0 + rank);
        perm[dstp] = gb * 64 + lane;
    }
}

// ---------------- grouped GEMM: direct-global fragments, zero-barrier K-loop ----------------
__global__ __launch_bounds__(256, 3) void moe_gemm(
    const unsigned short* __restrict__ xbf,
    const unsigned short* __restrict__ webt,
    const float* __restrict__ be,
    const int* __restrict__ perm,
    const int* __restrict__ eidx,
    float* __restrict__ out)
{
    __shared__ __align__(16) float ep_s[4 * 16 * 68];   // epilogue scratch only (17.4 KB)

    const int bid = blockIdx.x;
    // supertile XCD map: 4096 blocks = 8 XCD x 512; XCD owns 16mt x 32nt band,
    // walked in 8mt x 4nt supertiles of 32 (~3MB A+B working set per XCD < 4MB L2)
    const int xcd = bid & 7, idx = bid >> 3;
    const int st = idx >> 5, q = idx & 31;
    const int mt = xcd * 16 + (st >> 3) * 8 + (q >> 2);
    const int nt = (st & 7) * 4 + (q & 3);
    const int m0 = mt * 128, n0 = nt * 128;
    const int tid = threadIdx.x, lane = tid & 63, wid = tid >> 6;
    const int wm = wid >> 1, wn = wid & 1;

    // per-lane fragment base pointers: row = (lane&15) + frag*16; k-chunk = (lane>>4)*8
    const int lr = lane & 15, lg = lane >> 4;
    const unsigned short* pa[4];
#pragma unroll
    for (int mi = 0; mi < 4; ++mi) {
        int row = wm * 64 + lr + mi * 16;
        pa[mi] = xbf + (size_t)perm[m0 + row] * DM + lg * 8;
    }

    const int e_lo = eidx[perm[m0]];
    const int e_hi = eidx[perm[m0 + 127]];

    for (int e = e_lo; e <= e_hi; ++e) {
        const unsigned short* pb[4];
#pragma unroll
        for (int ni = 0; ni < 4; ++ni) {
            int row = n0 + wn * 64 + lr + ni * 16;
            pb[ni] = webt + (size_t)e * DH * DM + (size_t)row * DM + lg * 8;
        }

        f32x4 acc[4][4];
#pragma unroll
        for (int mi = 0; mi < 4; ++mi)
#pragma unroll
            for (int ni = 0; ni < 4; ++ni) acc[mi][ni] = 0.f;

#define LOADG(FA, FB, KT) { \
        _Pragma("unroll") \
        for (int mi = 0; mi < 4; ++mi) FA[mi] = *(const bf16x8*)(pa[mi] + (KT) * KS); \
        _Pragma("unroll") \
        for (int ni = 0; ni < 4; ++ni) FB[ni] = *(const bf16x8*)(pb[ni] + (KT) * KS); }

#define MM(FA, FB) { \
        __builtin_amdgcn_s_setprio(1); \
        _Pragma("unroll") \
        for (int mi = 0; mi < 4; ++mi) \
        _Pragma("unroll") \
            for (int ni = 0; ni < 4; ++ni) \
                acc[mi][ni] = __builtin_amdgcn_mfma_f32_16x16x32_bf16(FA[mi], FB[ni], acc[mi][ni], 0, 0, 0); \
        __builtin_amdgcn_s_setprio(0); }

        bf16x8 fa0[4], fb0[4], fa1[4], fb1[4];
        LOADG(fa0, fb0, 0);
#pragma unroll 1
        for (int kt = 0; kt < NS; kt += 2) {
            LOADG(fa1, fb1, kt + 1);            // in flight under MM(f0)
            MM(fa0, fb0);
            if (kt + 2 < NS) LOADG(fa0, fb0, kt + 2);   // in flight under MM(f1)
            MM(fa1, fb1);
        }
#undef LOADG
#undef MM

        // ---- epilogue: LDS transpose -> wide nontemporal stores ----
        __syncthreads();   // scratch reuse fence across e-iterations
        float* ep = ep_s + wid * (16 * 68);   // per-wave 16x64 f32, stride 68
        const int colb = n0 + wn * 64;
        float bev[4];
#pragma unroll
        for (int ni = 0; ni < 4; ++ni) bev[ni] = be[e * DH + colb + ni * 16 + lr];
        const bool multi = (e_lo != e_hi);
        const int rowb = m0 + wm * 64;

#pragma unroll
        for (int mi = 0; mi < 4; ++mi) {
            // scatter acc (D layout: row=(lane>>4)*4+r, col=ni*16+(lane&15)) into ep
#pragma unroll
            for (int ni = 0; ni < 4; ++ni)
#pragma unroll
                for (int r = 0; r < 4; ++r)
                    ep[(lg * 4 + r) * 68 + ni * 16 + lr] = acc[mi][ni][r] + bev[ni];
            // gather contiguous: lane -> row g*4+lg, cols lr*4..+4
#pragma unroll
            for (int g = 0; g < 4; ++g) {
                f32x4 v = *(const f32x4*)&ep[(g * 4 + lg) * 68 + lr * 4];
                int tk = perm[rowb + mi * 16 + g * 4 + lg];
                if (!multi || eidx[tk] == e)
                    __builtin_nontemporal_store(
                        v, (f32x4*)(out + (size_t)tk * DH + colb + lr * 4));
            }
        }
        __syncthreads();   // ep fully consumed before next e overwrites
    }
}

extern "C" void kernel_launch(void* const* d_in, const int* in_sizes, int n_in,
                              void* d_out, int out_size, void* d_ws, size_t ws_size,
                              hipStream_t stream) {
    const float* x  = (const float*)d_in[0];
    const float* Wg = (const float*)d_in[1];
    const float* bg = (const float*)d_in[2];
    const float* We = (const float*)d_in[3];
    const float* be = (const float*)d_in[4];
    float* out = (float*)d_out;
    int T = in_sizes[0] / DM;   // 16384

    char* ws = (char*)d_ws;
    int* cur  = (int*)ws;
    int* perm = (int*)(ws + 4096);
    int* eidx = (int*)(ws + 4096 + 65536);
    unsigned short* webt = (unsigned short*)(ws + 4096 + 2 * 65536);
    unsigned short* xbf  = (unsigned short*)(ws + 4096 + 2 * 65536 + (size_t)2 * DH * DM * 2);

    hipMemsetAsync(cur, 0, 8, stream);
    hipLaunchKernelGGL(prep, dim3(512 + T / 64), dim3(1024), 0, stream,
                       x, Wg, bg, We, T, xbf, webt, perm, eidx, cur);
    int nblk = (T / 128) * (DH / 128);   // 128 * 32 = 4096
    hipLaunchKernelGGL(moe_gemm, dim3(nblk), dim3(256), 0, stream,
                       xbf, webt, be, perm, eidx, out);
}

// Round 13
// 208.945 us; speedup vs baseline: 2.6897x; 2.6897x over previous
//
#include <hip/hip_runtime.h>
#include <hip/hip_bf16.h>

// MoE top-1, E=2: out[t,:] = x[t,:] @ We[e*] + be[e*],  e* = argmax(x[t]@Wg + bg)
//
// moe_gemm R13 = R9 (best verified: 209us total / 192us GEMM) minus s_setprio.
// T5 evidence (m190): setprio is null-to-NEGATIVE on lockstep ring GEMM
// structures (only pays on true 8-phase role-split schedules). All else
// byte-identical: 128x128 tile, BK=32, 4 waves, 3-slot LDS ring, reg-dbuf
// prefetch distance 3, vmcnt(4)-BEFORE-barrier, supertile XCD map,
// T2 swizzle f(row)=(row>>1)&3, LDS-transpose + nontemporal f32x4 epilogue.

#define DM 1024
#define DH 4096
#define KS 32
#define NS (DM / KS)   // 32 K-steps

typedef __attribute__((ext_vector_type(4))) float f32x4;
typedef __attribute__((ext_vector_type(8))) __bf16 bf16x8;

__device__ __forceinline__ unsigned short f2bf(float f) {
    union { float f; unsigned u; } a; a.f = f;
    unsigned u = a.u;
    u += 0x7fffu + ((u >> 16) & 1u);   // RNE
    return (unsigned short)(u >> 16);
}

__device__ __forceinline__ void gl16(const unsigned short* g, unsigned short* l) {
    __builtin_amdgcn_global_load_lds(
        (const __attribute__((address_space(1))) unsigned int*)(g),
        (__attribute__((address_space(3))) unsigned int*)(l), 16, 0, 0);
}

// ---------------- prep: We transpose (bid<512) | gate+convert+scatter (bid>=512) ----------------
__global__ __launch_bounds__(1024) void prep(
    const float* __restrict__ x, const float* __restrict__ Wg,
    const float* __restrict__ bg, const float* __restrict__ We, int T,
    unsigned short* __restrict__ xbf, unsigned short* __restrict__ webt,
    int* __restrict__ perm, int* __restrict__ eidx, int* __restrict__ cur)
{
    int bid = blockIdx.x, tid = threadIdx.x;

    if (bid < 512) {
        // ---- We [2][1024][4096] f32 -> webt [2][4096][1024] bf16, 4 64x64 tiles/block ----
        __shared__ unsigned short tile[4][64][72];
        int sub = tid >> 8, t2 = tid & 255;
        int g = bid * 4 + sub;
        int e = g >> 10, rr = g & 1023, kt = rr >> 6, ht = rr & 63;
        int k0 = kt * 64, h0 = ht * 64;
        int k = t2 >> 2, hc = t2 & 3;
        const float* src = We + ((size_t)e * DM + k0 + k) * DH + h0 + hc * 16;
#pragma unroll
        for (int j = 0; j < 4; ++j) {
            f32x4 v = *(const f32x4*)(src + j * 4);
#pragma unroll
            for (int q = 0; q < 4; ++q)
                tile[sub][hc * 16 + j * 4 + q][k] = f2bf(v[q]);
        }
        __syncthreads();
        int h = t2 >> 2, kc = t2 & 3;
        unsigned short* dst = webt + ((size_t)e * DH + h0 + h) * DM + k0 + kc * 16;
        *(uint4*)(dst)     = *(const uint4*)&tile[sub][h][kc * 16];
        *(uint4*)(dst + 8) = *(const uint4*)&tile[sub][h][kc * 16 + 8];
        return;
    }

    // ---- gate: 64 tokens/block, 16 waves x 4 tokens; 2 atomics/block (G12) ----
    __shared__ unsigned char eL[64];
    int gb = bid - 512;                 // 0..255
    int lane = tid & 63, w = tid >> 6;  // 16 waves
    float wgv[32];                      // Wg rows 2c,2c+1 for this lane's 16 cols
#pragma unroll
    for (int j = 0; j < 8; ++j)
        *(f32x4*)&wgv[j * 4] = *(const f32x4*)(Wg + lane * 32 + j * 4);
    float bg0 = bg[0], bg1 = bg[1];
    int t0 = gb * 64 + w * 4;
#pragma unroll
    for (int tl = 0; tl < 4; ++tl) {
        int t = t0 + tl;
        const float* xr = x + (size_t)t * DM + lane * 16;
        double g0 = 0.0, g1 = 0.0;
        unsigned hw[8];
#pragma unroll
        for (int j = 0; j < 4; ++j) {
            f32x4 v = *(const f32x4*)(xr + j * 4);
#pragma unroll
            for (int q = 0; q < 4; ++q) {
                g0 += (double)v[q] * (double)wgv[2 * (j * 4 + q)];
                g1 += (double)v[q] * (double)wgv[2 * (j * 4 + q) + 1];
            }
            hw[j * 2]     = (unsigned)f2bf(v[0]) | ((unsigned)f2bf(v[1]) << 16);
            hw[j * 2 + 1] = (unsigned)f2bf(v[2]) | ((unsigned)f2bf(v[3]) << 16);
        }
        unsigned short* xw = xbf + (size_t)t * DM + lane * 16;
        uint4 u0; u0.x = hw[0]; u0.y = hw[1]; u0.z = hw[2]; u0.w = hw[3];
        uint4 u1; u1.x = hw[4]; u1.y = hw[5]; u1.z = hw[6]; u1.w = hw[7];
        *(uint4*)(xw)     = u0;
        *(uint4*)(xw + 8) = u1;
#pragma unroll
        for (int off = 32; off; off >>= 1) {
            g0 += __shfl_xor(g0, off);
            g1 += __shfl_xor(g1, off);
        }
        if (lane == 0) {
            int ee = ((g1 + (double)bg1) > (g0 + (double)bg0)) ? 1 : 0;  // tie -> e0
            eidx[t] = ee;
            eL[w * 4 + tl] = (unsigned char)ee;
        }
    }
    __syncthreads();
    if (w == 0) {
        int myE = eL[lane];
        unsigned long long m1 = __ballot(myE != 0);
        int tot1 = __popcll(m1);
        int b0 = 0, b1 = 0;
        if (lane == 0) {
            b0 = atomicAdd(cur, 64 - tot1);
            b1 = atomicAdd(cur + 1, tot1);
        }
        b0 = __shfl(b0, 0);
        b1 = __shfl(b1, 0);
        unsigned long long lm = (1ull << lane) - 1ull;
        int rank = __popcll((myE ? m1 : ~m1) & lm);
        int dstp = myE ? (T - b1 - tot1 + rank) : (b0 + rank);
        perm[dstp] = gb * 64 + lane;
    }
}

// ---------------- grouped GEMM: reg-dbuf + distance-3 ring, vmcnt-before-barrier ----------------
__global__ __launch_bounds__(256, 3) void moe_gemm(
    const unsigned short* __restrict__ xbf,
    const unsigned short* __restrict__ webt,
    const float* __restrict__ be,
    const int* __restrict__ perm,
    const int* __restrict__ eidx,
    float* __restrict__ out)
{
    __shared__ __align__(16) char smem[3 * 16384];   // 48 KB: 3 x (A 8KB | B 8KB)

    const int bid = blockIdx.x;
    // supertile XCD map: 4096 blocks = 8 XCD x 512; XCD owns 16mt x 32nt band,
    // walked in 8mt x 4nt supertiles of 32 (~3MB A+B working set per XCD < 4MB L2)
    const int xcd = bid & 7, idx = bid >> 3;
    const int st = idx >> 5, q = idx & 31;
    const int mt = xcd * 16 + (st >> 3) * 8 + (q >> 2);
    const int nt = (st & 7) * 4 + (q & 3);
    const int m0 = mt * 128, n0 = nt * 128;
    const int tid = threadIdx.x, lane = tid & 63, wid = tid >> 6;
    const int wm = wid >> 1, wn = wid & 1;

    // staging: 512 granules(16B) per operand; granule c=[row=c>>2][phys=c&3],
    // source k8 = phys ^ ((row>>1)&3)  (inverse swizzle on SOURCE, linear LDS dest)
    const unsigned short *aptr0, *aptr1;
    size_t bofs0, bofs1;
    {
        int c0 = tid, c1 = tid + 256;
        int r0 = c0 >> 2, k80 = (c0 & 3) ^ ((r0 >> 1) & 3);
        int r1 = c1 >> 2, k81 = (c1 & 3) ^ ((r1 >> 1) & 3);
        aptr0 = xbf + (size_t)perm[m0 + r0] * DM + k80 * 8;
        aptr1 = xbf + (size_t)perm[m0 + r1] * DM + k81 * 8;
        bofs0 = (size_t)(n0 + r0) * DM + k80 * 8;
        bofs1 = (size_t)(n0 + r1) * DM + k81 * 8;
    }

    // fragment read offsets: slot = (lane>>4) ^ ((row>>1)&3); invariant over mi/ni (rows step 16)
    const int rA = wm * 64 + (lane & 15);
    const int rB = wn * 64 + (lane & 15);
    const int offA = rA * KS + (((lane >> 4) ^ ((rA >> 1) & 3)) * 8);
    const int offB = rB * KS + (((lane >> 4) ^ ((rB >> 1) & 3)) * 8);

    const int e_lo = eidx[perm[m0]];
    const int e_hi = eidx[perm[m0 + 127]];

    for (int e = e_lo; e <= e_hi; ++e) {
        const unsigned short* wb = webt + (size_t)e * DH * DM;

        __syncthreads();   // LDS reuse fence (epilogue scratch / prev e readers)

        // prologue: stage K0,K1,K2 into slots 0,1,2 (12 loads)
#pragma unroll
        for (int s = 0; s < 3; ++s) {
            unsigned short* Asl = (unsigned short*)(smem + s * 16384);
            unsigned short* Bsl = (unsigned short*)(smem + s * 16384 + 8192);
            gl16(aptr0 + s * KS, Asl + tid * 8);
            gl16(aptr1 + s * KS, Asl + (tid + 256) * 8);
            gl16(wb + bofs0 + s * KS, Bsl + tid * 8);
            gl16(wb + bofs1 + s * KS, Bsl + (tid + 256) * 8);
        }

        f32x4 acc[4][4];
#pragma unroll
        for (int mi = 0; mi < 4; ++mi)
#pragma unroll
            for (int ni = 0; ni < 4; ++ni) acc[mi][ni] = 0.f;

        asm volatile("s_waitcnt vmcnt(4)" ::: "memory");   // K0,K1 landed (all waves pre-barrier)
        __builtin_amdgcn_s_barrier();

        bf16x8 fa0[4], fb0[4], fa1[4], fb1[4];   // two named fragment sets (no dyn idx)
        {   // preload K0 fragments from slot 0
            const unsigned short* As = (const unsigned short*)(smem);
            const unsigned short* Bs = (const unsigned short*)(smem + 8192);
#pragma unroll
            for (int mi = 0; mi < 4; ++mi) fa0[mi] = *(const bf16x8*)(As + offA + mi * 16 * KS);
#pragma unroll
            for (int ni = 0; ni < 4; ++ni) fb0[ni] = *(const bf16x8*)(Bs + offB + ni * 16 * KS);
        }

        // iter kt: gl16 K(kt+3)->slot kt%3 | ds_read slot(kt+1) -> next | MFMA(cur)
        //          | vmcnt(4) | s_barrier
        auto step = [&](int kt, bf16x8 (&ca)[4], bf16x8 (&cb)[4],
                        bf16x8 (&na)[4], bf16x8 (&nb)[4]) {
            if (kt + 3 < NS) {
                int sl = kt % 3;
                unsigned short* Asl = (unsigned short*)(smem + sl * 16384);
                unsigned short* Bsl = (unsigned short*)(smem + sl * 16384 + 8192);
                gl16(aptr0 + (kt + 3) * KS, Asl + tid * 8);
                gl16(aptr1 + (kt + 3) * KS, Asl + (tid + 256) * 8);
                gl16(wb + bofs0 + (kt + 3) * KS, Bsl + tid * 8);
                gl16(wb + bofs1 + (kt + 3) * KS, Bsl + (tid + 256) * 8);
            }
            if (kt + 1 < NS) {
                int sl = (kt + 1) % 3;
                const unsigned short* As = (const unsigned short*)(smem + sl * 16384);
                const unsigned short* Bs = (const unsigned short*)(smem + sl * 16384 + 8192);
#pragma unroll
                for (int mi = 0; mi < 4; ++mi) na[mi] = *(const bf16x8*)(As + offA + mi * 16 * KS);
#pragma unroll
                for (int ni = 0; ni < 4; ++ni) nb[ni] = *(const bf16x8*)(Bs + offB + ni * 16 * KS);
            }
#pragma unroll
            for (int mi = 0; mi < 4; ++mi)
#pragma unroll
                for (int ni = 0; ni < 4; ++ni)
                    acc[mi][ni] = __builtin_amdgcn_mfma_f32_16x16x32_bf16(
                        ca[mi], cb[ni], acc[mi][ni], 0, 0, 0);
            __builtin_amdgcn_sched_barrier(0);
            // vmcnt BEFORE barrier: all waves' K(kt+2) in LDS once everyone passes
            if (kt < NS - 3)       asm volatile("s_waitcnt vmcnt(4)" ::: "memory");
            else if (kt == NS - 3) asm volatile("s_waitcnt vmcnt(0)" ::: "memory");
            __builtin_amdgcn_s_barrier();
            __builtin_amdgcn_sched_barrier(0);
        };

#pragma unroll 1
        for (int kt = 0; kt < NS; kt += 2) {
            step(kt,     fa0, fb0, fa1, fb1);
            step(kt + 1, fa1, fb1, fa0, fb0);
        }

        // ---- epilogue: LDS transpose -> wide nontemporal stores ----
        __syncthreads();   // all lgkm/vm drained; safe to reuse smem as scratch
        float* ep = (float*)smem + wid * (16 * 68);   // per-wave 16x64 f32, stride 68
        const int colb = n0 + wn * 64;
        float bev[4];
#pragma unroll
        for (int ni = 0; ni < 4; ++ni) bev[ni] = be[e * DH + colb + ni * 16 + (lane & 15)];
        const bool multi = (e_lo != e_hi);
        const int rowb = m0 + wm * 64;

#pragma unroll
        for (int mi = 0; mi < 4; ++mi) {
            // scatter acc (D layout: row=(lane>>4)*4+r, col=ni*16+(lane&15)) into ep
#pragma unroll
            for (int ni = 0; ni < 4; ++ni)
#pragma unroll
                for (int r = 0; r < 4; ++r)
                    ep[((lane >> 4) * 4 + r) * 68 + ni * 16 + (lane & 15)] =
                        acc[mi][ni][r] + bev[ni];
            // gather contiguous: lane -> row g*4+(lane>>4), cols (lane&15)*4..+4
#pragma unroll
            for (int g = 0; g < 4; ++g) {
                f32x4 v = *(const f32x4*)&ep[(g * 4 + (lane >> 4)) * 68 + (lane & 15) * 4];
                int tk = perm[rowb + mi * 16 + g * 4 + (lane >> 4)];
                if (!multi || eidx[tk] == e)
                    __builtin_nontemporal_store(
                        v, (f32x4*)(out + (size_t)tk * DH + colb + (lane & 15) * 4));
            }
        }
    }
}

extern "C" void kernel_launch(void* const* d_in, const int* in_sizes, int n_in,
                              void* d_out, int out_size, void* d_ws, size_t ws_size,
                              hipStream_t stream) {
    const float* x  = (const float*)d_in[0];
    const float* Wg = (const float*)d_in[1];
    const float* bg = (const float*)d_in[2];
    const float* We = (const float*)d_in[3];
    const float* be = (const float*)d_in[4];
    float* out = (float*)d_out;
    int T = in_sizes[0] / DM;   // 16384

    char* ws = (char*)d_ws;
    int* cur  = (int*)ws;
    int* perm = (int*)(ws + 4096);
    int* eidx = (int*)(ws + 4096 + 65536);
    unsigned short* webt = (unsigned short*)(ws + 4096 + 2 * 65536);
    unsigned short* xbf  = (unsigned short*)(ws + 4096 + 2 * 65536 + (size_t)2 * DH * DM * 2);

    hipMemsetAsync(cur, 0, 8, stream);
    hipLaunchKernelGGL(prep, dim3(512 + T / 64), dim3(1024), 0, stream,
                       x, Wg, bg, We, T, xbf, webt, perm, eidx, cur);
    int nblk = (T / 128) * (DH / 128);   // 128 * 32 = 4096
    hipLaunchKernelGGL(moe_gemm, dim3(nblk), dim3(256), 0, stream,
                       xbf, webt, be, perm, eidx, out);
}